// Round 3
// baseline (1446.608 us; speedup 1.0000x reference)
//
#include <hip/hip_runtime.h>

// ---------------------------------------------------------------------------
// 3-state pair-HMM forward DP (logsumexp semiring), skewed band pipeline.
//   24 bands x 64 rows, one 64-lane wave per band. Lane r owns row 64b+r+1,
//   at step t computes column j = (t - r) + 1. up/diag flow via DPP wave_shr.
//   Band handoff through global `bottom` rows + agent-scope progress flags.
// R7: R6 failed (absmax 368). Root-cause audit: the only unverified
//   mechanism was the 12-byte global_load_lds feed DMA (guide measures only
//   4B/16B). If HW lane-stride for 12B is 16B (padded dwordx3), feed col 0
//   reads correctly and later cols read shifted garbage -> moderate error,
//   matching the signature. Fix: feed rides the VERIFIED 4B DMA -- lanes
//   0..23 carry one float each (k=L/3, r=L%3, src bsrc[jn*3+r]), LDS dest
//   uniform base + L*4B == linear slot k*3+r, exactly the read layout.
//   Theta 16B/4B staging, counted vmcnt (40/41/25), DPP shuffle unchanged.
// ---------------------------------------------------------------------------

#define MM 1536
#define HH 64
#define NB 24
#define U  8
#define NBLK 200                    // 200*8 = 1600 >= MM+HH-1 = 1599 steps
#define LOG2E 1.4426950408889634f
#define LN2   0.6931471805599453f
#define NEG2  (-1.4426950408889634e8f)   // (-1e8) * LOG2E (log2-domain -inf)

// LDS layout (floats):
//   theta buf in {0,1}: base = buf*4608, col k block = k*576:
//     [0,256)   q0 floats 0..3, lane L at +L*4   (16B DMA)
//     [256,512) q1 floats 4..7, lane L at +L*4   (16B DMA)
//     [512,576) s8 float  8,    lane L at +L     (4B DMA)
//   feed  buf in {0,1}: base = 9216 + buf*64, slot k*3+r (4B DMA, lane k*3+r)
#define LDS_TH  4608
#define LDS_FD  9216
#define LDS_FDB 64

typedef float f32x4 __attribute__((ext_vector_type(4)));
typedef float f32x2 __attribute__((ext_vector_type(2)));

template <int BYTES>
__device__ __forceinline__ void gl_lds(const float* g, float* l) {
    auto* gp = (const __attribute__((address_space(1))) float*)(g);
    auto* lp = (__attribute__((address_space(3))) float*)(l);
    if constexpr (BYTES == 16) __builtin_amdgcn_global_load_lds(gp, lp, 16, 0, 0);
    else                       __builtin_amdgcn_global_load_lds(gp, lp, 4, 0, 0);
}

__device__ __forceinline__ float shup1(float x) {
    // lane L gets lane L-1's x (DPP wave_shr:1, crosses row boundaries);
    // lane 0 keeps its own value (old operand) -- always overwritten by the
    // feed select. row_shr:N == "lane i reads lane i-N" (GCN scan idiom).
    int xi = __builtin_bit_cast(int, x);
    int r  = __builtin_amdgcn_update_dpp(xi, xi, 0x138, 0xF, 0xF, false);
    return __builtin_bit_cast(float, r);
}

__device__ __forceinline__ float lse3_2(float a, float b, float c) {
    // log2-domain LSE of 3: max3 + med3 + min3 (hw ops), 2 exp2 + 1 log2.
    float mx = fmaxf(fmaxf(a, b), c);
    float mn = fminf(fminf(a, b), c);
    float md = __builtin_amdgcn_fmed3f(a, b, c);
    return mx + __builtin_amdgcn_logf(1.0f + __builtin_amdgcn_exp2f(mn - mx)
                                           + __builtin_amdgcn_exp2f(md - mx));
}

__global__ void init_progress_kernel(int* progress) {
    if (threadIdx.x < NB) progress[threadIdx.x] = -1;
}

__global__ __launch_bounds__(64, 1)
void hmm_fwd_kernel(const float* __restrict__ theta, float* __restrict__ out,
                    float* __restrict__ bottom, int* __restrict__ progress)
{
    __shared__ __align__(16) float smem[2 * LDS_TH + 2 * LDS_FDB];  // 37,376 B

    const int b    = blockIdx.x;
    const int lane = threadIdx.x;
    const float* __restrict__ thp = theta + (size_t)(b * HH + lane) * (MM * 9);
    const float* __restrict__ bsrc =
        bottom + (size_t)(b > 0 ? b - 1 : 0) * ((MM + 1) * 3);
    float* __restrict__ bdst = bottom + (size_t)b * ((MM + 1) * 3);

    float d0, d1, d2, l0, l1, l2, s0, s1, s2, res0, res1, res2;
    d0 = d1 = d2 = (b == 0 && lane == 0) ? 0.0f : NEG2;   // V[0,0] = 0 border
    l0 = l1 = l2 = NEG2;
    s0 = s1 = s2 = NEG2;
    res0 = res1 = res2 = NEG2;

    // feed lane split: lane L<24 carries feed[k][r], k=L/3, r=L%3
    const int fidx = lane < 24 ? lane : 23;
    const int fk   = fidx / 3;
    const int fr   = fidx - fk * 3;

    // Issue the DMA for the block whose first column is `tb`, into buffer nb.
    auto issue_block = [&](int tb, int nb) {
        #pragma unroll
        for (int k = 0; k < U; ++k) {
            int c = tb + k - lane;
            c = c < 0 ? 0 : (c > MM - 1 ? MM - 1 : c);   // clamp addr only
            const float* g = thp + (size_t)c * 9;
            float* base = &smem[nb * LDS_TH + k * 576];
            gl_lds<16>(g,     base);         // lane writes base + lane*16B
            gl_lds<16>(g + 4, base + 256);
            gl_lds<4 >(g + 8, base + 512);   // lane writes +lane*4B
        }
        if (b > 0) {
            int jn = tb + fk + 1; if (jn > MM) jn = MM;
            // lane L<24 -> slot L = k*3+r (linear); lanes 24..63 dup into
            // never-read slots 24..63 (buffer is 64 floats).
            gl_lds<4>(bsrc + (size_t)jn * 3 + fr, &smem[LDS_FD + nb * LDS_FDB]);
        }
    };

    // pre-loop sync: covers prime (j<=8) + T=0 issue (j<=16) + T=1 (j<=24)
    if (b > 0) {
        while (__hip_atomic_load(&progress[b - 1], __ATOMIC_ACQUIRE,
                                 __HIP_MEMORY_SCOPE_AGENT) < 24)
            __builtin_amdgcn_s_sleep(2);
    }

    // prime block 0 into buffer 0; full drain once (only cold stall)
    issue_block(0, 0);
    asm volatile("s_waitcnt vmcnt(0)" ::: "memory");
    __builtin_amdgcn_sched_barrier(0);

    auto block_body = [&](int T, int cb) {
        const int t0 = T * U;
        const int nb = cb ^ 1;

        // consumer poll (even blocks): guarantee feed cols through t0+24,
        // covering the feed DMAs issued at tops of blocks T and T+1.
        if (b > 0 && T > 0 && (T & 1) == 0) {
            int need = t0 + 24; if (need > MM) need = MM;
            while (__hip_atomic_load(&progress[b - 1], __ATOMIC_ACQUIRE,
                                     __HIP_MEMORY_SCOPE_AGENT) < need)
                __builtin_amdgcn_s_sleep(2);
        }

        // issue L(T+1) into the other buffer (in flight across this block)
        issue_block(t0 + U, nb);

        // drain L(T). vmcnt retires in order; ops issued after L(T) are
        // S(T-1)=16 asm stores + L(T+1)=24/25 DMAs, so leaving that many
        // outstanding drains exactly L(T). Counts are deterministic.
        if (b == 0)          asm volatile("s_waitcnt vmcnt(40)" ::: "memory");
        else if (b < NB - 1) asm volatile("s_waitcnt vmcnt(41)" ::: "memory");
        else                 asm volatile("s_waitcnt vmcnt(25)" ::: "memory");
        __builtin_amdgcn_sched_barrier(0);

        // compute 8 columns from LDS buffer cb
        #pragma unroll
        for (int k = 0; k < U; ++k) {
            const int c = t0 + k - lane;
            const bool act = ((unsigned)c < (unsigned)MM);

            const float* tb_ = &smem[cb * LDS_TH + k * 576];
            f32x4 q0 = *(const f32x4*)(tb_ + lane * 4);
            f32x4 q1 = *(const f32x4*)(tb_ + 256 + lane * 4);
            float s8 = tb_[512 + lane];

            float f0 = NEG2, f1 = NEG2, f2 = NEG2;
            if (b > 0) {
                const float* fb = &smem[LDS_FD + cb * LDS_FDB + k * 3];
                f0 = fb[0]; f1 = fb[1]; f2 = fb[2];
            }

            float u0 = (lane == 0) ? f0 : s0;
            float u1 = (lane == 0) ? f1 : s1;
            float u2 = (lane == 0) ? f2 : s2;

            float aa0 = fmaf(q0.x, LOG2E, d0);
            float aa1 = fmaf(q0.y, LOG2E, d1);
            float aa2 = fmaf(q0.z, LOG2E, d2);
            float bb0 = fmaf(q0.w, LOG2E, u0);
            float bb1 = fmaf(q1.x, LOG2E, u1);
            float bb2 = fmaf(q1.y, LOG2E, u2);
            float cc0 = fmaf(q1.z, LOG2E, l0);
            float cc1 = fmaf(q1.w, LOG2E, l1);
            float cc2 = fmaf(s8,   LOG2E, l2);

            float n0 = lse3_2(aa0, aa1, aa2);
            float n1 = lse3_2(bb0, bb1, bb2);
            float n2 = lse3_2(cc0, cc1, cc2);
            n0 = act ? n0 : NEG2;
            n1 = act ? n1 : NEG2;
            n2 = act ? n2 : NEG2;

            // producer: lane 63 streams this band's bottom row. Inline-asm
            // stores, DETERMINISTIC count (16/block): inactive columns dump
            // masked NEG2 into slot j=0, which no consumer reads (jn >= 1).
            if (b < NB - 1 && lane == HH - 1) {
                const int j = act ? c + 1 : 0;
                float* sa = bdst + (size_t)j * 3;
                f32x2 p01; p01.x = n0; p01.y = n1;
                asm volatile("global_store_dwordx2 %0, %1, off"
                             :: "v"(sa), "v"(p01) : "memory");
                asm volatile("global_store_dword %0, %1, off offset:8"
                             :: "v"(sa), "v"(n2) : "memory");
            }

            // capture V[N,M] (c == MM-1 on lane 63 of band NB-1)
            const bool fin = (c == MM - 1);
            res0 = fin ? n0 : res0;
            res1 = fin ? n1 : res1;
            res2 = fin ? n2 : res2;

            // rotate wavefront state
            d0 = u0; d1 = u1; d2 = u2;
            s0 = shup1(n0);
            s1 = shup1(n1);
            s2 = shup1(n2);
            l0 = n0; l1 = n1; l2 = n2;
        }

        // publish progress every 2 blocks. vmcnt(0) is cheap here: the only
        // older loads (L(T+1)) are a full compute-block old; just the fresh
        // S(T) stores drain.
        if (b < NB - 1 && lane == HH - 1 && (T & 1) == 1) {
            int val = t0 - 55;                 // j_last = (t0+7) - 63 + 1
            if (val >= 1) {
                if (val > MM) val = MM;
                asm volatile("s_waitcnt vmcnt(0)" ::: "memory");
                __hip_atomic_store(&progress[b], val, __ATOMIC_RELEASE,
                                   __HIP_MEMORY_SCOPE_AGENT);
            }
        }
    };

    for (int T2 = 0; T2 < NBLK; T2 += 2) {
        block_body(T2,     0);
        block_body(T2 + 1, 1);
    }

    if (b == NB - 1 && lane == HH - 1)
        out[0] = LN2 * lse3_2(res0, res1, res2);
}

extern "C" void kernel_launch(void* const* d_in, const int* in_sizes, int n_in,
                              void* d_out, int out_size, void* d_ws, size_t ws_size,
                              hipStream_t stream)
{
    const float* theta = (const float*)d_in[0];
    float* out = (float*)d_out;

    float* bottom   = (float*)d_ws;                       // 24*1537*3 floats
    int*   progress = (int*)((char*)d_ws +
                             (size_t)NB * (MM + 1) * 3 * sizeof(float));

    init_progress_kernel<<<1, 64, 0, stream>>>(progress);
    hmm_fwd_kernel<<<NB, HH, 0, stream>>>(theta, out, bottom, progress);
}

// Round 4
// 1078.898 us; speedup vs baseline: 1.3408x; 1.3408x over previous
//
#include <hip/hip_runtime.h>

// ---------------------------------------------------------------------------
// 3-state pair-HMM forward DP (logsumexp semiring), skewed band pipeline.
//   24 bands x 64 rows, one 64-lane wave per band. Lane r owns row 64b+r+1,
//   at step t computes column j = (t - r) + 1. up/diag flow via DPP wave_shr.
//   Band handoff through global `bottom` rows + agent-scope progress flags.
// R8: R7's 860 cy/col decomposed: ~170 VALU + ~190 exposed LDS reads +
//   publish vmcnt(0) full drains (drain the just-issued DMA scatter) +
//   poll round trips + mask overhead. Fixes:
//   (1) software-pipelined LDS->reg: cold-read col 0 after the top wait,
//       prefetch col k+1 during col k's compute (LDS latency hidden).
//   (2) bottom stores are device-scope (sc1) -> visible once vmcnt-retired;
//       publish = counted vmcnt(16) + RELAXED atomic store at TOP of block
//       before L(T+1) issue. Queue there = [P(T-1), L(T), S(T-1)]; leaving
//       16 outstanding drains exactly L(T)+S(<=T-2)+P — the one counted
//       wait per block replaces both old waits. val = t0-71 (covers through
//       block T-2's stores). Final publish post-loop = release + vmcnt(0).
//   (3) head/mid/tail loop split: blocks 8..191 (92%) drop act-masking and
//       fin-capture entirely (only lane63/band23's res matters, t=1598).
// ---------------------------------------------------------------------------

#define MM 1536
#define HH 64
#define NB 24
#define U  8
#define NBLK 200                    // 200*8 = 1600 >= MM+HH-1 = 1599 steps
#define LOG2E 1.4426950408889634f
#define LN2   0.6931471805599453f
#define NEG2  (-1.4426950408889634e8f)   // (-1e8) * LOG2E (log2-domain -inf)

// LDS layout (floats):
//   theta buf in {0,1}: base = buf*4608, col k block = k*576:
//     [0,256)   q0 floats 0..3, lane L at +L*4   (16B DMA)
//     [256,512) q1 floats 4..7, lane L at +L*4   (16B DMA)
//     [512,576) s8 float  8,    lane L at +L     (4B DMA)
//   feed  buf in {0,1}: base = 9216 + buf*64, slot k*3+r (4B DMA, lane k*3+r)
#define LDS_TH  4608
#define LDS_FD  9216
#define LDS_FDB 64

typedef float f32x4 __attribute__((ext_vector_type(4)));
typedef float f32x2 __attribute__((ext_vector_type(2)));

template <int BYTES>
__device__ __forceinline__ void gl_lds(const float* g, float* l) {
    auto* gp = (const __attribute__((address_space(1))) float*)(g);
    auto* lp = (__attribute__((address_space(3))) float*)(l);
    if constexpr (BYTES == 16) __builtin_amdgcn_global_load_lds(gp, lp, 16, 0, 0);
    else                       __builtin_amdgcn_global_load_lds(gp, lp, 4, 0, 0);
}

__device__ __forceinline__ float shup1(float x) {
    // lane L gets lane L-1's x (DPP wave_shr:1); lane 0 keeps its own value
    // (always overwritten by the feed select). Verified R7 (absmax 0).
    int xi = __builtin_bit_cast(int, x);
    int r  = __builtin_amdgcn_update_dpp(xi, xi, 0x138, 0xF, 0xF, false);
    return __builtin_bit_cast(float, r);
}

__device__ __forceinline__ float lse3_2(float a, float b, float c) {
    // log2-domain LSE of 3: max3 + med3 + min3 (hw ops), 2 exp2 + 1 log2.
    float mx = fmaxf(fmaxf(a, b), c);
    float mn = fminf(fminf(a, b), c);
    float md = __builtin_amdgcn_fmed3f(a, b, c);
    return mx + __builtin_amdgcn_logf(1.0f + __builtin_amdgcn_exp2f(mn - mx)
                                           + __builtin_amdgcn_exp2f(md - mx));
}

__global__ void init_progress_kernel(int* progress) {
    if (threadIdx.x < NB) progress[threadIdx.x] = -1;
}

__global__ __launch_bounds__(64, 1)
void hmm_fwd_kernel(const float* __restrict__ theta, float* __restrict__ out,
                    float* __restrict__ bottom, int* __restrict__ progress)
{
    __shared__ __align__(16) float smem[2 * LDS_TH + 2 * LDS_FDB];  // 37,376 B

    const int b    = blockIdx.x;
    const int lane = threadIdx.x;
    const float* __restrict__ thp = theta + (size_t)(b * HH + lane) * (MM * 9);
    const float* __restrict__ bsrc =
        bottom + (size_t)(b > 0 ? b - 1 : 0) * ((MM + 1) * 3);
    float* __restrict__ bdst = bottom + (size_t)b * ((MM + 1) * 3);

    float d0, d1, d2, l0, l1, l2, s0, s1, s2, res0, res1, res2;
    d0 = d1 = d2 = (b == 0 && lane == 0) ? 0.0f : NEG2;   // V[0,0] = 0 border
    l0 = l1 = l2 = NEG2;
    s0 = s1 = s2 = NEG2;
    res0 = res1 = res2 = NEG2;

    // feed lane split: lane L<24 carries feed[k][r], k=L/3, r=L%3
    const int fidx = lane < 24 ? lane : 23;
    const int fk   = fidx / 3;
    const int fr   = fidx - fk * 3;

    auto issue_block = [&](int tb, int nbuf) {
        #pragma unroll
        for (int k = 0; k < U; ++k) {
            int c = tb + k - lane;
            c = c < 0 ? 0 : (c > MM - 1 ? MM - 1 : c);   // clamp addr only
            const float* g = thp + (size_t)c * 9;
            float* base = &smem[nbuf * LDS_TH + k * 576];
            gl_lds<16>(g,     base);         // lane writes base + lane*16B
            gl_lds<16>(g + 4, base + 256);
            gl_lds<4 >(g + 8, base + 512);   // lane writes +lane*4B
        }
        if (b > 0) {
            int jn = tb + fk + 1; if (jn > MM) jn = MM;
            gl_lds<4>(bsrc + (size_t)jn * 3 + fr, &smem[LDS_FD + nbuf * LDS_FDB]);
        }
    };

    // pre-loop sync: covers prime (j<=8) + T=0 issue (j<=16) + T=1 (j<=24)
    if (b > 0) {
        while (__hip_atomic_load(&progress[b - 1], __ATOMIC_ACQUIRE,
                                 __HIP_MEMORY_SCOPE_AGENT) < 24)
            __builtin_amdgcn_s_sleep(2);
    }

    // prime block 0 into buffer 0; full drain once (only cold stall)
    issue_block(0, 0);
    asm volatile("s_waitcnt vmcnt(0)" ::: "memory");
    __builtin_amdgcn_sched_barrier(0);

    auto block_body = [&](int T, int cb, bool mlo, bool mhi) {
        const int t0 = T * U;
        const int nbuf = cb ^ 1;

        // consumer poll (even blocks): guarantee feed cols through t0+24,
        // covering the feed DMAs issued at blocks T and T+1.
        if (b > 0 && T > 0 && (T & 1) == 0) {
            int need = t0 + 24; if (need > MM) need = MM;
            while (__hip_atomic_load(&progress[b - 1], __ATOMIC_ACQUIRE,
                                     __HIP_MEMORY_SCOPE_AGENT) < need)
                __builtin_amdgcn_s_sleep(2);
        }

        // ONE counted wait per block. Queue here (issue order):
        // [P(T-1), L(T), S(T-1)=16]. Leaving 16 outstanding retires exactly
        // S(T-1)'s predecessors: L(T) (this block's data) and S(<=T-2)+P.
        if (b < NB - 1) asm volatile("s_waitcnt vmcnt(16)" ::: "memory");
        else            asm volatile("s_waitcnt vmcnt(0)"  ::: "memory");

        // issue L(T+1) into the other buffer (in flight across this block)
        issue_block(t0 + U, nbuf);

        // publish: S(<=T-2) are sc1 (device-scope: globally visible once
        // vmcnt-retired, done by the wait above) -> RELAXED store suffices.
        // val = t0-71 covers columns through block T-2 (lane63 col t0-8-63).
        if (b < NB - 1 && lane == HH - 1) {
            int val = t0 - 71;
            if (val >= 1) {
                if (val > MM) val = MM;
                __hip_atomic_store(&progress[b], val, __ATOMIC_RELAXED,
                                   __HIP_MEMORY_SCOPE_AGENT);
            }
        }
        __builtin_amdgcn_sched_barrier(0);

        // ---- software-pipelined compute: cold-read col 0, prefetch k+1 ----
        const float* base  = &smem[cb * LDS_TH];
        const float* fbase = &smem[LDS_FD + cb * LDS_FDB];
        f32x4 q0 = *(const f32x4*)(base + lane * 4);
        f32x4 q1 = *(const f32x4*)(base + 256 + lane * 4);
        float s8 = base[512 + lane];
        float f0 = NEG2, f1 = NEG2, f2 = NEG2;
        if (b > 0) { f0 = fbase[0]; f1 = fbase[1]; f2 = fbase[2]; }

        #pragma unroll
        for (int k = 0; k < U; ++k) {
            f32x4 q0n, q1n; float s8n, f0n = NEG2, f1n = NEG2, f2n = NEG2;
            if (k < U - 1) {                       // prefetch col k+1
                const float* cp = base + (k + 1) * 576;
                q0n = *(const f32x4*)(cp + lane * 4);
                q1n = *(const f32x4*)(cp + 256 + lane * 4);
                s8n = cp[512 + lane];
                if (b > 0) {
                    f0n = fbase[(k + 1) * 3];
                    f1n = fbase[(k + 1) * 3 + 1];
                    f2n = fbase[(k + 1) * 3 + 2];
                }
            }

            const int c = t0 + k - lane;
            bool act = true;
            if (mlo || mhi) act = ((unsigned)c < (unsigned)MM);

            float u0 = (lane == 0) ? f0 : s0;
            float u1 = (lane == 0) ? f1 : s1;
            float u2 = (lane == 0) ? f2 : s2;

            float aa0 = fmaf(q0.x, LOG2E, d0);
            float aa1 = fmaf(q0.y, LOG2E, d1);
            float aa2 = fmaf(q0.z, LOG2E, d2);
            float bb0 = fmaf(q0.w, LOG2E, u0);
            float bb1 = fmaf(q1.x, LOG2E, u1);
            float bb2 = fmaf(q1.y, LOG2E, u2);
            float cc0 = fmaf(q1.z, LOG2E, l0);
            float cc1 = fmaf(q1.w, LOG2E, l1);
            float cc2 = fmaf(s8,   LOG2E, l2);

            float n0 = lse3_2(aa0, aa1, aa2);
            float n1 = lse3_2(bb0, bb1, bb2);
            float n2 = lse3_2(cc0, cc1, cc2);
            if (mlo || mhi) {
                n0 = act ? n0 : NEG2;
                n1 = act ? n1 : NEG2;
                n2 = act ? n2 : NEG2;
            }

            // producer: lane 63 streams the bottom row. sc1 = device scope,
            // visible once vmcnt-retired. DETERMINISTIC 16 stores/block:
            // inactive columns dump into never-read slot j=0.
            if (b < NB - 1 && lane == HH - 1) {
                int j = c + 1;
                if (mlo || mhi) j = act ? c + 1 : 0;
                float* sa = bdst + (size_t)j * 3;
                f32x2 p01; p01.x = n0; p01.y = n1;
                asm volatile("global_store_dwordx2 %0, %1, off sc1"
                             :: "v"(sa), "v"(p01) : "memory");
                asm volatile("global_store_dword %0, %1, off offset:8 sc1"
                             :: "v"(sa), "v"(n2) : "memory");
            }

            if (mhi) {   // capture V[N,M]: lane63 hits c==MM-1 at T=199
                const bool fin = (c == MM - 1);
                res0 = fin ? n0 : res0;
                res1 = fin ? n1 : res1;
                res2 = fin ? n2 : res2;
            }

            // rotate wavefront state
            d0 = u0; d1 = u1; d2 = u2;
            s0 = shup1(n0);
            s1 = shup1(n1);
            s2 = shup1(n2);
            l0 = n0; l1 = n1; l2 = n2;

            if (k < U - 1) {
                q0 = q0n; q1 = q1n; s8 = s8n;
                f0 = f0n; f1 = f1n; f2 = f2n;
            }
        }
    };

    // head (mask low edge) / mid (no mask, no fin) / tail (mask high + fin).
    // c range: T>=8 -> c >= 64-63 = 1 >= 0; T<=191 -> c <= 1528+7 = 1535 < MM.
    for (int T = 0;   T < 8;    ++T) block_body(T, T & 1, true,  false);
    for (int T = 8;   T < 192;  ++T) block_body(T, T & 1, false, false);
    for (int T = 192; T < NBLK; ++T) block_body(T, T & 1, false, true);

    // final publish: release + full drain (bulletproof tail handoff)
    if (b < NB - 1 && lane == HH - 1) {
        asm volatile("s_waitcnt vmcnt(0)" ::: "memory");
        __hip_atomic_store(&progress[b], MM, __ATOMIC_RELEASE,
                           __HIP_MEMORY_SCOPE_AGENT);
    }

    if (b == NB - 1 && lane == HH - 1)
        out[0] = LN2 * lse3_2(res0, res1, res2);
}

extern "C" void kernel_launch(void* const* d_in, const int* in_sizes, int n_in,
                              void* d_out, int out_size, void* d_ws, size_t ws_size,
                              hipStream_t stream)
{
    const float* theta = (const float*)d_in[0];
    float* out = (float*)d_out;

    float* bottom   = (float*)d_ws;                       // 24*1537*3 floats
    int*   progress = (int*)((char*)d_ws +
                             (size_t)NB * (MM + 1) * 3 * sizeof(float));

    init_progress_kernel<<<1, 64, 0, stream>>>(progress);
    hmm_fwd_kernel<<<NB, HH, 0, stream>>>(theta, out, bottom, progress);
}

// Round 5
// 1039.919 us; speedup vs baseline: 1.3911x; 1.0375x over previous
//
#include <hip/hip_runtime.h>

// ---------------------------------------------------------------------------
// 3-state pair-HMM forward DP (logsumexp semiring), skewed band pipeline.
//   24 bands x 64 rows, one 64-lane wave per band. Lane r owns row 64b+r+1,
//   at step t computes column j = (t - r) + 1. up/diag flow via DPP wave_shr.
//   Band handoff through global `bottom` rows + agent-scope progress flags.
// R9: R5..R8 all plateau at ~1050-1150 us because theta staging is perfectly
//   UNCOALESCED (lane = row, rows 55 KB apart): 24 DMAs x 64 scattered lines
//   = 1536 L1 transactions per 8-col block -- the invariant cost across all
//   staging mechanisms. Fix: a one-shot full-chip transpose kernel
//   (skew_kernel, 38592 waves, latency-immaterial) rewrites theta into
//   band-skewed records: skew[b][t] = 2304 B contiguous = the exact q0/q1/s8
//   LDS image of the column the DP wave needs at step t (out-of-range cells
//   = 0.0, masked by existing head/tail logic). DP staging becomes 18
//   contiguous 1-KB global_load_lds DMAs per block (~300 dense transactions,
//   HBM-streamed). Compute loop, feed, counted-vmcnt + sc1 publish protocol
//   are byte-for-byte R8; wait constant (leave S(T-1)=16) is DMA-count
//   independent. ws_size checked host-side (needs 89 MB) with exact-R8
//   fallback (template<false>).
// ---------------------------------------------------------------------------

#define MM 1536
#define HH 64
#define NB 24
#define U  8
#define NBLK 200                    // 200*8 = 1600 >= MM+HH-1 = 1599 steps
#define NSTEP 1608                  // staged t range: 0..1607 (incl. prefetch)
#define LOG2E 1.4426950408889634f
#define LN2   0.6931471805599453f
#define NEG2  (-1.4426950408889634e8f)   // (-1e8) * LOG2E (log2-domain -inf)

// LDS layout (floats):
//   theta buf in {0,1}: base = buf*4608, col k block = k*576:
//     [0,256)   q0 floats 0..3, lane L at +L*4
//     [256,512) q1 floats 4..7, lane L at +L*4
//     [512,576) s8 float  8,    lane L at +L
//   skew[b][t] in global memory is EXACTLY this 576-float image -> staging
//   is a linear 2304-B copy (18 x 1KB DMAs cover a whole 8-col block).
//   feed  buf in {0,1}: base = 9216 + buf*64, slot k*3+r (4B DMA, lane k*3+r)
#define LDS_TH  4608
#define LDS_FD  9216
#define LDS_FDB 64

typedef float f32x4 __attribute__((ext_vector_type(4)));
typedef float f32x2 __attribute__((ext_vector_type(2)));

template <int BYTES>
__device__ __forceinline__ void gl_lds(const float* g, float* l) {
    auto* gp = (const __attribute__((address_space(1))) float*)(g);
    auto* lp = (__attribute__((address_space(3))) float*)(l);
    if constexpr (BYTES == 16) __builtin_amdgcn_global_load_lds(gp, lp, 16, 0, 0);
    else                       __builtin_amdgcn_global_load_lds(gp, lp, 4, 0, 0);
}

__device__ __forceinline__ float shup1(float x) {
    // lane L gets lane L-1's x (DPP wave_shr:1); lane 0 keeps its own value
    // (always overwritten by the feed select). Verified R7/R8 (absmax 0).
    int xi = __builtin_bit_cast(int, x);
    int r  = __builtin_amdgcn_update_dpp(xi, xi, 0x138, 0xF, 0xF, false);
    return __builtin_bit_cast(float, r);
}

__device__ __forceinline__ float lse3_2(float a, float b, float c) {
    // log2-domain LSE of 3: max3 + med3 + min3 (hw ops), 2 exp2 + 1 log2.
    float mx = fmaxf(fmaxf(a, b), c);
    float mn = fminf(fminf(a, b), c);
    float md = __builtin_amdgcn_fmed3f(a, b, c);
    return mx + __builtin_amdgcn_logf(1.0f + __builtin_amdgcn_exp2f(mn - mx)
                                           + __builtin_amdgcn_exp2f(md - mx));
}

__global__ void init_progress_kernel(int* progress) {
    if (threadIdx.x < NB) progress[threadIdx.x] = -1;
}

// ---------------------------------------------------------------------------
// skew_kernel: one wave per (band b, step t). Lane r reads theta record
// (row 64b+r, col t-r) -- scattered reads, but 38592 concurrent waves hide
// everything -- and writes the 2304-B skewed record with coalesced stores.
// ---------------------------------------------------------------------------
__global__ __launch_bounds__(256)
void skew_kernel(const float* __restrict__ theta, float* __restrict__ skew)
{
    const int wid  = blockIdx.x * 4 + (threadIdx.x >> 6);
    const int lane = threadIdx.x & 63;
    const int b = wid / NSTEP;
    const int t = wid - b * NSTEP;

    const int c = t - lane;
    float v[9];
    if ((unsigned)c < (unsigned)MM) {
        const float* g = theta + ((size_t)(b * HH + lane) * MM + c) * 9;
        __builtin_memcpy(&v[0], g, 36);
    } else {
        #pragma unroll
        for (int i = 0; i < 9; ++i) v[i] = 0.0f;
    }

    float* o = skew + (size_t)(b * NSTEP + t) * 576;
    f32x4 a; a.x = v[0]; a.y = v[1]; a.z = v[2]; a.w = v[3];
    f32x4 q; q.x = v[4]; q.y = v[5]; q.z = v[6]; q.w = v[7];
    *(f32x4*)(o + lane * 4)       = a;   // coalesced 1 KB
    *(f32x4*)(o + 256 + lane * 4) = q;   // coalesced 1 KB
    o[512 + lane] = v[8];                // coalesced 256 B
}

template <bool SKEW>
__global__ __launch_bounds__(64, 1)
void hmm_fwd_kernel(const float* __restrict__ src, float* __restrict__ out,
                    float* __restrict__ bottom, int* __restrict__ progress)
{
    __shared__ __align__(16) float smem[2 * LDS_TH + 2 * LDS_FDB];  // 37,376 B

    const int b    = blockIdx.x;
    const int lane = threadIdx.x;
    const float* __restrict__ thp =
        SKEW ? nullptr : src + (size_t)(b * HH + lane) * (MM * 9);
    const float* __restrict__ skp =
        SKEW ? src + (size_t)b * NSTEP * 576 : nullptr;
    const float* __restrict__ bsrc =
        bottom + (size_t)(b > 0 ? b - 1 : 0) * ((MM + 1) * 3);
    float* __restrict__ bdst = bottom + (size_t)b * ((MM + 1) * 3);

    float d0, d1, d2, l0, l1, l2, s0, s1, s2, res0, res1, res2;
    d0 = d1 = d2 = (b == 0 && lane == 0) ? 0.0f : NEG2;   // V[0,0] = 0 border
    l0 = l1 = l2 = NEG2;
    s0 = s1 = s2 = NEG2;
    res0 = res1 = res2 = NEG2;

    // feed lane split: lane L<24 carries feed[k][r], k=L/3, r=L%3
    const int fidx = lane < 24 ? lane : 23;
    const int fk   = fidx / 3;
    const int fr   = fidx - fk * 3;

    auto issue_block = [&](int tb, int nbuf) {
        if constexpr (SKEW) {
            // 8 cols x 2304 B contiguous = 18 x 1-KB dense DMAs.
            // tb+7 <= 1607 < NSTEP always -> no clamp needed.
            const float* g0 = skp + (size_t)tb * 576 + lane * 4;
            float* l0_ = &smem[nbuf * LDS_TH];
            #pragma unroll
            for (int d = 0; d < 18; ++d)
                gl_lds<16>(g0 + d * 256, l0_ + d * 256);
        } else {
            #pragma unroll
            for (int k = 0; k < U; ++k) {
                int c = tb + k - lane;
                c = c < 0 ? 0 : (c > MM - 1 ? MM - 1 : c);   // clamp addr only
                const float* g = thp + (size_t)c * 9;
                float* base = &smem[nbuf * LDS_TH + k * 576];
                gl_lds<16>(g,     base);
                gl_lds<16>(g + 4, base + 256);
                gl_lds<4 >(g + 8, base + 512);
            }
        }
        if (b > 0) {
            int jn = tb + fk + 1; if (jn > MM) jn = MM;
            gl_lds<4>(bsrc + (size_t)jn * 3 + fr, &smem[LDS_FD + nbuf * LDS_FDB]);
        }
    };

    // pre-loop sync: covers prime (j<=8) + T=0 issue (j<=16) + T=1 (j<=24)
    if (b > 0) {
        while (__hip_atomic_load(&progress[b - 1], __ATOMIC_ACQUIRE,
                                 __HIP_MEMORY_SCOPE_AGENT) < 24)
            __builtin_amdgcn_s_sleep(2);
    }

    // prime block 0 into buffer 0; full drain once (only cold stall)
    issue_block(0, 0);
    asm volatile("s_waitcnt vmcnt(0)" ::: "memory");
    __builtin_amdgcn_sched_barrier(0);

    auto block_body = [&](int T, int cb, bool mlo, bool mhi) {
        const int t0 = T * U;
        const int nbuf = cb ^ 1;

        // consumer poll (even blocks): guarantee feed cols through t0+24,
        // covering the feed DMAs issued at blocks T and T+1.
        if (b > 0 && T > 0 && (T & 1) == 0) {
            int need = t0 + 24; if (need > MM) need = MM;
            while (__hip_atomic_load(&progress[b - 1], __ATOMIC_ACQUIRE,
                                     __HIP_MEMORY_SCOPE_AGENT) < need)
                __builtin_amdgcn_s_sleep(2);
        }

        // ONE counted wait per block. Queue here (issue order):
        // [P(T-1), L(T), S(T-1)=16]. Leaving 16 outstanding retires exactly
        // S(T-1)'s predecessors: L(T) (this block's data) and S(<=T-2)+P.
        // Constant is DMA-count independent (= stores left outstanding).
        if (b < NB - 1) asm volatile("s_waitcnt vmcnt(16)" ::: "memory");
        else            asm volatile("s_waitcnt vmcnt(0)"  ::: "memory");

        // issue L(T+1) into the other buffer (in flight across this block)
        issue_block(t0 + U, nbuf);

        // publish: S(<=T-2) are sc1 (device-scope: globally visible once
        // vmcnt-retired, done by the wait above) -> RELAXED store suffices.
        // val = t0-71 covers columns through block T-2 (lane63 col t0-8-63).
        if (b < NB - 1 && lane == HH - 1) {
            int val = t0 - 71;
            if (val >= 1) {
                if (val > MM) val = MM;
                __hip_atomic_store(&progress[b], val, __ATOMIC_RELAXED,
                                   __HIP_MEMORY_SCOPE_AGENT);
            }
        }
        __builtin_amdgcn_sched_barrier(0);

        // ---- software-pipelined compute: cold-read col 0, prefetch k+1 ----
        const float* base  = &smem[cb * LDS_TH];
        const float* fbase = &smem[LDS_FD + cb * LDS_FDB];
        f32x4 q0 = *(const f32x4*)(base + lane * 4);
        f32x4 q1 = *(const f32x4*)(base + 256 + lane * 4);
        float s8 = base[512 + lane];
        float f0 = NEG2, f1 = NEG2, f2 = NEG2;
        if (b > 0) { f0 = fbase[0]; f1 = fbase[1]; f2 = fbase[2]; }

        #pragma unroll
        for (int k = 0; k < U; ++k) {
            f32x4 q0n, q1n; float s8n, f0n = NEG2, f1n = NEG2, f2n = NEG2;
            if (k < U - 1) {                       // prefetch col k+1
                const float* cp = base + (k + 1) * 576;
                q0n = *(const f32x4*)(cp + lane * 4);
                q1n = *(const f32x4*)(cp + 256 + lane * 4);
                s8n = cp[512 + lane];
                if (b > 0) {
                    f0n = fbase[(k + 1) * 3];
                    f1n = fbase[(k + 1) * 3 + 1];
                    f2n = fbase[(k + 1) * 3 + 2];
                }
            }

            const int c = t0 + k - lane;
            bool act = true;
            if (mlo || mhi) act = ((unsigned)c < (unsigned)MM);

            float u0 = (lane == 0) ? f0 : s0;
            float u1 = (lane == 0) ? f1 : s1;
            float u2 = (lane == 0) ? f2 : s2;

            float aa0 = fmaf(q0.x, LOG2E, d0);
            float aa1 = fmaf(q0.y, LOG2E, d1);
            float aa2 = fmaf(q0.z, LOG2E, d2);
            float bb0 = fmaf(q0.w, LOG2E, u0);
            float bb1 = fmaf(q1.x, LOG2E, u1);
            float bb2 = fmaf(q1.y, LOG2E, u2);
            float cc0 = fmaf(q1.z, LOG2E, l0);
            float cc1 = fmaf(q1.w, LOG2E, l1);
            float cc2 = fmaf(s8,   LOG2E, l2);

            float n0 = lse3_2(aa0, aa1, aa2);
            float n1 = lse3_2(bb0, bb1, bb2);
            float n2 = lse3_2(cc0, cc1, cc2);
            if (mlo || mhi) {
                n0 = act ? n0 : NEG2;
                n1 = act ? n1 : NEG2;
                n2 = act ? n2 : NEG2;
            }

            // producer: lane 63 streams the bottom row. sc1 = device scope,
            // visible once vmcnt-retired. DETERMINISTIC 16 stores/block:
            // inactive columns dump into never-read slot j=0.
            if (b < NB - 1 && lane == HH - 1) {
                int j = c + 1;
                if (mlo || mhi) j = act ? c + 1 : 0;
                float* sa = bdst + (size_t)j * 3;
                f32x2 p01; p01.x = n0; p01.y = n1;
                asm volatile("global_store_dwordx2 %0, %1, off sc1"
                             :: "v"(sa), "v"(p01) : "memory");
                asm volatile("global_store_dword %0, %1, off offset:8 sc1"
                             :: "v"(sa), "v"(n2) : "memory");
            }

            if (mhi) {   // capture V[N,M]: lane63 hits c==MM-1 at T=199
                const bool fin = (c == MM - 1);
                res0 = fin ? n0 : res0;
                res1 = fin ? n1 : res1;
                res2 = fin ? n2 : res2;
            }

            // rotate wavefront state
            d0 = u0; d1 = u1; d2 = u2;
            s0 = shup1(n0);
            s1 = shup1(n1);
            s2 = shup1(n2);
            l0 = n0; l1 = n1; l2 = n2;

            if (k < U - 1) {
                q0 = q0n; q1 = q1n; s8 = s8n;
                f0 = f0n; f1 = f1n; f2 = f2n;
            }
        }
    };

    // head (mask low edge) / mid (no mask, no fin) / tail (mask high + fin).
    // c range: T>=8 -> c >= 64-63 = 1 >= 0; T<=191 -> c <= 1528+7 = 1535 < MM.
    for (int T = 0;   T < 8;    ++T) block_body(T, T & 1, true,  false);
    for (int T = 8;   T < 192;  ++T) block_body(T, T & 1, false, false);
    for (int T = 192; T < NBLK; ++T) block_body(T, T & 1, false, true);

    // final publish: release + full drain (bulletproof tail handoff)
    if (b < NB - 1 && lane == HH - 1) {
        asm volatile("s_waitcnt vmcnt(0)" ::: "memory");
        __hip_atomic_store(&progress[b], MM, __ATOMIC_RELEASE,
                           __HIP_MEMORY_SCOPE_AGENT);
    }

    if (b == NB - 1 && lane == HH - 1)
        out[0] = LN2 * lse3_2(res0, res1, res2);
}

extern "C" void kernel_launch(void* const* d_in, const int* in_sizes, int n_in,
                              void* d_out, int out_size, void* d_ws, size_t ws_size,
                              hipStream_t stream)
{
    const float* theta = (const float*)d_in[0];
    float* out = (float*)d_out;

    const size_t skew_fl = (size_t)NB * NSTEP * 576;      // 88.9 MB
    const size_t bot_fl  = (size_t)NB * (MM + 1) * 3;     // 442 KB
    const size_t need    = (skew_fl + bot_fl) * sizeof(float) + NB * sizeof(int);

    if (ws_size >= need) {
        float* skew     = (float*)d_ws;
        float* bottom   = skew + skew_fl;
        int*   progress = (int*)(bottom + bot_fl);
        init_progress_kernel<<<1, 64, 0, stream>>>(progress);
        skew_kernel<<<(NB * NSTEP) / 4, 256, 0, stream>>>(theta, skew);
        hmm_fwd_kernel<true><<<NB, HH, 0, stream>>>(skew, out, bottom, progress);
    } else {
        float* bottom   = (float*)d_ws;
        int*   progress = (int*)((char*)d_ws + bot_fl * sizeof(float));
        init_progress_kernel<<<1, 64, 0, stream>>>(progress);
        hmm_fwd_kernel<false><<<NB, HH, 0, stream>>>(theta, out, bottom, progress);
    }
}

// Round 8
// 1004.672 us; speedup vs baseline: 1.4399x; 1.0351x over previous
//
#include <hip/hip_runtime.h>

// ---------------------------------------------------------------------------
// 3-state pair-HMM forward DP (logsumexp semiring), skewed band pipeline.
//   24 bands x 64 rows, one 64-lane wave per band. Lane r owns row 64b+r+1,
//   at step t computes column j = (t - r) + 1. up/diag flow via DPP wave_shr.
//   Band handoff through global `bottom` rows + agent-scope progress flags.
// R12: R10/R11 failed identically (absmax 96) -> the asm-LDS-read machinery
//   is buggy in a way two audits didn't find. LDS staging is not load-
//   bearing (76 floats/lane working set) -- drop it. Compose the two
//   PROVEN-CORRECT pieces instead:
//   (1) R5 (absmax 0): asm global_load into registers, issued one block
//       ahead, counted vmcnt. (2) R9 (absmax 0): skew_kernel pre-transposes
//       theta so the wave's loads are dense/coalesced (3 loads/col: dwordx4,
//       dwordx4 offset:1024, dword; each = contiguous 1 KB per wave).
//   Wait-first vmcnt(16) (leave S(T-1)=16 outstanding) is robust to
//   compiler-inserted feed loads: anything issued during block T-1's
//   compute is NEWER than L(T), so draining to <=16 always retires L(T)
//   fully, and S(<=T-2) (older than L(T)) is retired for the publish.
//   No __shared__, no ds_read, no LDS init -> R10/R11's failure surface
//   is gone. Feed = R5's plain memcpy; publish/poll = R8/R9 protocol;
//   DPP shup1, head/mid/tail split, sc1 stores unchanged.
// ---------------------------------------------------------------------------

#define MM 1536
#define HH 64
#define NB 24
#define U  8
#define NBLK 200                    // 200*8 = 1600 >= MM+HH-1 = 1599 steps
#define NSTEP 1608                  // staged t range: 0..1607 (incl. prefetch)
#define LOG2E 1.4426950408889634f
#define LN2   0.6931471805599453f
#define NEG2  (-1.4426950408889634e8f)   // (-1e8) * LOG2E (log2-domain -inf)

typedef float f32x4 __attribute__((ext_vector_type(4)));
typedef float f32x2 __attribute__((ext_vector_type(2)));

struct T9R { f32x4 q0; f32x4 q1; float s8; };   // one column, this lane's row
struct F3R { float v0, v1, v2; };               // bottom-row feed triple

__device__ __forceinline__ float shup1(float x) {
    // lane L gets lane L-1's x (DPP wave_shr:1); lane 0 keeps its own value
    // (always overwritten by the feed select). Verified R7-R9 (absmax 0).
    int xi = __builtin_bit_cast(int, x);
    int r  = __builtin_amdgcn_update_dpp(xi, xi, 0x138, 0xF, 0xF, false);
    return __builtin_bit_cast(float, r);
}

__device__ __forceinline__ float lse3_2(float a, float b, float c) {
    // log2-domain LSE of 3: max3 + med3 + min3 (hw ops), 2 exp2 + 1 log2.
    float mx = fmaxf(fmaxf(a, b), c);
    float mn = fminf(fminf(a, b), c);
    float md = __builtin_amdgcn_fmed3f(a, b, c);
    return mx + __builtin_amdgcn_logf(1.0f + __builtin_amdgcn_exp2f(mn - mx)
                                           + __builtin_amdgcn_exp2f(md - mx));
}

__global__ void init_progress_kernel(int* progress) {
    if (threadIdx.x < NB) progress[threadIdx.x] = -1;
}

// ---------------------------------------------------------------------------
// skew_kernel (PROVEN R9): one wave per (band b, step t). Lane r reads theta
// record (row 64b+r, col t-r) -- scattered, hidden by 38592 concurrent
// waves -- writes the 2304-B skewed record with coalesced stores.
// Record layout (floats): [0,256) q0 (lane*4), [256,512) q1, [512,576) s8.
// ---------------------------------------------------------------------------
__global__ __launch_bounds__(256)
void skew_kernel(const float* __restrict__ theta, float* __restrict__ skew)
{
    const int wid  = blockIdx.x * 4 + (threadIdx.x >> 6);
    const int lane = threadIdx.x & 63;
    const int b = wid / NSTEP;
    const int t = wid - b * NSTEP;

    const int c = t - lane;
    float v[9];
    if ((unsigned)c < (unsigned)MM) {
        const float* g = theta + ((size_t)(b * HH + lane) * MM + c) * 9;
        __builtin_memcpy(&v[0], g, 36);
    } else {
        #pragma unroll
        for (int i = 0; i < 9; ++i) v[i] = 0.0f;
    }

    float* o = skew + (size_t)(b * NSTEP + t) * 576;
    f32x4 a; a.x = v[0]; a.y = v[1]; a.z = v[2]; a.w = v[3];
    f32x4 q; q.x = v[4]; q.y = v[5]; q.z = v[6]; q.w = v[7];
    *(f32x4*)(o + lane * 4)       = a;   // coalesced 1 KB
    *(f32x4*)(o + 256 + lane * 4) = q;   // coalesced 1 KB
    o[512 + lane] = v[8];                // coalesced 256 B
}

template <bool SKEW>
__global__ __launch_bounds__(64, 1)
void hmm_fwd_kernel(const float* __restrict__ src, float* __restrict__ out,
                    float* __restrict__ bottom, int* __restrict__ progress)
{
    const int b    = blockIdx.x;
    const int lane = threadIdx.x;
    const float* __restrict__ thp =
        SKEW ? nullptr : src + (size_t)(b * HH + lane) * (MM * 9);
    const float* __restrict__ skp =
        SKEW ? src + (size_t)b * NSTEP * 576 : nullptr;
    const float* __restrict__ bsrc =
        bottom + (size_t)(b > 0 ? b - 1 : 0) * ((MM + 1) * 3);
    float* __restrict__ bdst = bottom + (size_t)b * ((MM + 1) * 3);

    float d0, d1, d2, l0, l1, l2, s0, s1, s2, res0, res1, res2;
    d0 = d1 = d2 = (b == 0 && lane == 0) ? 0.0f : NEG2;   // V[0,0] = 0 border
    l0 = l1 = l2 = NEG2;
    s0 = s1 = s2 = NEG2;
    res0 = res1 = res2 = NEG2;

    T9R thA[U], thB[U];       // theta double buffer (registers)
    F3R fdA[U], fdB[U];       // feed double buffer (registers)
    #pragma unroll
    for (int k = 0; k < U; ++k) {
        fdA[k].v0 = fdA[k].v1 = fdA[k].v2 = NEG2;   // band 0 border: -inf
        fdB[k].v0 = fdB[k].v1 = fdB[k].v2 = NEG2;
    }

    // issue theta loads for the block starting at step tb into nx (asm =
    // cannot be sunk/serialized; SKEW path is fully coalesced: each load is
    // a contiguous 1-KB wave transaction).
    auto issue_theta = [&](int tb, T9R (&nx)[U]) {
        if constexpr (SKEW) {
            #pragma unroll
            for (int k = 0; k < U; ++k) {
                const float* rec = skp + (size_t)(tb + k) * 576;
                const float* aq  = rec + (size_t)lane * 4;        // 16B/lane
                const float* as_ = rec + 512 + lane;              // 4B/lane
                asm volatile("global_load_dwordx4 %0, %1, off"
                             : "=v"(nx[k].q0) : "v"(aq));
                asm volatile("global_load_dwordx4 %0, %1, off offset:1024"
                             : "=v"(nx[k].q1) : "v"(aq));
                asm volatile("global_load_dword %0, %1, off"
                             : "=v"(nx[k].s8) : "v"(as_));
            }
        } else {
            // fallback (ws too small): scattered per-lane loads, compiler-
            // tracked (R4 behavior: correct, slower).
            #pragma unroll
            for (int k = 0; k < U; ++k) {
                int c = tb + k - lane;
                c = c < 0 ? 0 : (c > MM - 1 ? MM - 1 : c);
                __builtin_memcpy(&thA[0], &thA[0], 0);  // no-op keepalive
                struct P { float f[9]; } tmp;
                __builtin_memcpy(&tmp, thp + (size_t)c * 9, 36);
                nx[k].q0.x = tmp.f[0]; nx[k].q0.y = tmp.f[1];
                nx[k].q0.z = tmp.f[2]; nx[k].q0.w = tmp.f[3];
                nx[k].q1.x = tmp.f[4]; nx[k].q1.y = tmp.f[5];
                nx[k].q1.z = tmp.f[6]; nx[k].q1.w = tmp.f[7];
                nx[k].s8   = tmp.f[8];
            }
        }
    };
    auto issue_feed = [&](int tb, F3R (&fx)[U]) {
        if (b > 0) {
            #pragma unroll
            for (int k = 0; k < U; ++k) {
                int jn = tb + k + 1; if (jn > MM) jn = MM;
                __builtin_memcpy(&fx[k], bsrc + (size_t)jn * 3, 12);
            }
        }
    };

    // pre-loop sync: covers prime (j<=8) + T=0 issue (j<=16) + T=1 (j<=24)
    if (b > 0) {
        while (__hip_atomic_load(&progress[b - 1], __ATOMIC_ACQUIRE,
                                 __HIP_MEMORY_SCOPE_AGENT) < 24)
            __builtin_amdgcn_s_sleep(2);
    }

    // prime block 0 into the A buffers; full drain once (only cold stall)
    issue_theta(0, thA);
    issue_feed(0, fdA);
    asm volatile("s_waitcnt vmcnt(0)" ::: "memory");
    __builtin_amdgcn_sched_barrier(0);

    auto block_body = [&](int T, T9R (&cur)[U], T9R (&nxt)[U],
                          F3R (&fcur)[U], F3R (&fnxt)[U],
                          bool mlo, bool mhi) {
        const int t0 = T * U;

        // consumer poll (even blocks): guarantee feed cols through t0+24,
        // covering the feed loads issued at blocks T and T+1.
        if (b > 0 && T > 0 && (T & 1) == 0) {
            int need = t0 + 24; if (need > MM) need = MM;
            while (__hip_atomic_load(&progress[b - 1], __ATOMIC_ACQUIRE,
                                     __HIP_MEMORY_SCOPE_AGENT) < need)
                __builtin_amdgcn_s_sleep(2);
        }

        // ONE counted wait per block, BEFORE issuing L(T+1).
        // Every op issued during block T-1 (stores S(T-1)=16, publish, feed
        // loads) is NEWER than L(T) (issued at T-1's top), so draining to
        // <=16 always retires L(T) fully; S(<=T-2) (older than L(T)) is
        // also retired -> publish below is safe. Count is robust to any
        // compiler-inserted loads (they only make the wait stricter).
        if (b < NB - 1) asm volatile("s_waitcnt vmcnt(16)" ::: "memory");
        else            asm volatile("s_waitcnt vmcnt(0)"  ::: "memory");

        // issue L(T+1) (in flight across this whole block's compute)
        issue_theta(t0 + U, nxt);
        issue_feed(t0 + U, fnxt);

        // publish: sc1 stores are device-visible once vmcnt-retired (done
        // above for S(<=T-2)) -> RELAXED store suffices. val = t0-71 covers
        // columns through block T-2 (lane63's last col there = t0-72).
        if (b < NB - 1 && lane == HH - 1) {
            int val = t0 - 71;
            if (val >= 1) {
                if (val > MM) val = MM;
                __hip_atomic_store(&progress[b], val, __ATOMIC_RELAXED,
                                   __HIP_MEMORY_SCOPE_AGENT);
            }
        }
        __builtin_amdgcn_sched_barrier(0);

        // compute 8 columns from the current (resident) register buffers
        #pragma unroll
        for (int k = 0; k < U; ++k) {
            const int c = t0 + k - lane;
            bool act = true;
            if (mlo || mhi) act = ((unsigned)c < (unsigned)MM);

            float u0 = (lane == 0) ? fcur[k].v0 : s0;
            float u1 = (lane == 0) ? fcur[k].v1 : s1;
            float u2 = (lane == 0) ? fcur[k].v2 : s2;

            float aa0 = fmaf(cur[k].q0.x, LOG2E, d0);
            float aa1 = fmaf(cur[k].q0.y, LOG2E, d1);
            float aa2 = fmaf(cur[k].q0.z, LOG2E, d2);
            float bb0 = fmaf(cur[k].q0.w, LOG2E, u0);
            float bb1 = fmaf(cur[k].q1.x, LOG2E, u1);
            float bb2 = fmaf(cur[k].q1.y, LOG2E, u2);
            float cc0 = fmaf(cur[k].q1.z, LOG2E, l0);
            float cc1 = fmaf(cur[k].q1.w, LOG2E, l1);
            float cc2 = fmaf(cur[k].s8,   LOG2E, l2);

            float n0 = lse3_2(aa0, aa1, aa2);
            float n1 = lse3_2(bb0, bb1, bb2);
            float n2 = lse3_2(cc0, cc1, cc2);
            if (mlo || mhi) {
                n0 = act ? n0 : NEG2;
                n1 = act ? n1 : NEG2;
                n2 = act ? n2 : NEG2;
            }

            // producer: lane 63 streams the bottom row. sc1 = device scope.
            // DETERMINISTIC 16 stores/block: inactive cols -> slot j=0
            // (never read; feeds start at jn>=1).
            if (b < NB - 1 && lane == HH - 1) {
                int j = c + 1;
                if (mlo || mhi) j = act ? c + 1 : 0;
                float* sa = bdst + (size_t)j * 3;
                f32x2 p01; p01.x = n0; p01.y = n1;
                asm volatile("global_store_dwordx2 %0, %1, off sc1"
                             :: "v"(sa), "v"(p01) : "memory");
                asm volatile("global_store_dword %0, %1, off offset:8 sc1"
                             :: "v"(sa), "v"(n2) : "memory");
            }

            if (mhi) {   // capture V[N,M]: lane63 hits c==MM-1 at T=199
                const bool fin = (c == MM - 1);
                res0 = fin ? n0 : res0;
                res1 = fin ? n1 : res1;
                res2 = fin ? n2 : res2;
            }

            // rotate wavefront state
            d0 = u0; d1 = u1; d2 = u2;
            s0 = shup1(n0);
            s1 = shup1(n1);
            s2 = shup1(n2);
            l0 = n0; l1 = n1; l2 = n2;
        }
    };

    // head (mask low edge) / mid (no mask, no fin) / tail (mask high + fin).
    // c range: T>=8 -> c >= 64-63 = 1 >= 0; T<=191 -> c <= 1528+7 = 1535 < MM.
    for (int T = 0; T < 8; T += 2) {
        block_body(T,     thA, thB, fdA, fdB, true, false);
        block_body(T + 1, thB, thA, fdB, fdA, true, false);
    }
    for (int T = 8; T < 192; T += 2) {
        block_body(T,     thA, thB, fdA, fdB, false, false);
        block_body(T + 1, thB, thA, fdB, fdA, false, false);
    }
    for (int T = 192; T < NBLK; T += 2) {
        block_body(T,     thA, thB, fdA, fdB, false, true);
        block_body(T + 1, thB, thA, fdB, fdA, false, true);
    }

    // final publish: release + full drain (bulletproof tail handoff)
    if (b < NB - 1 && lane == HH - 1) {
        asm volatile("s_waitcnt vmcnt(0)" ::: "memory");
        __hip_atomic_store(&progress[b], MM, __ATOMIC_RELEASE,
                           __HIP_MEMORY_SCOPE_AGENT);
    }

    if (b == NB - 1 && lane == HH - 1)
        out[0] = LN2 * lse3_2(res0, res1, res2);
}

extern "C" void kernel_launch(void* const* d_in, const int* in_sizes, int n_in,
                              void* d_out, int out_size, void* d_ws, size_t ws_size,
                              hipStream_t stream)
{
    const float* theta = (const float*)d_in[0];
    float* out = (float*)d_out;

    const size_t skew_fl = (size_t)NB * NSTEP * 576;      // 88.9 MB
    const size_t bot_fl  = (size_t)NB * (MM + 1) * 3;     // 442 KB
    const size_t need    = (skew_fl + bot_fl) * sizeof(float) + NB * sizeof(int);

    if (ws_size >= need) {
        float* skew     = (float*)d_ws;
        float* bottom   = skew + skew_fl;
        int*   progress = (int*)(bottom + bot_fl);
        init_progress_kernel<<<1, 64, 0, stream>>>(progress);
        skew_kernel<<<(NB * NSTEP) / 4, 256, 0, stream>>>(theta, skew);
        hmm_fwd_kernel<true><<<NB, HH, 0, stream>>>(skew, out, bottom, progress);
    } else {
        float* bottom   = (float*)d_ws;
        int*   progress = (int*)((char*)d_ws + bot_fl * sizeof(float));
        init_progress_kernel<<<1, 64, 0, stream>>>(progress);
        hmm_fwd_kernel<false><<<NB, HH, 0, stream>>>(theta, out, bottom, progress);
    }
}

// Round 9
// 893.382 us; speedup vs baseline: 1.6192x; 1.1246x over previous
//
#include <hip/hip_runtime.h>

// ---------------------------------------------------------------------------
// 3-state pair-HMM forward DP (logsumexp semiring), skewed band pipeline.
//   24 bands x 64 rows, one 64-lane wave per band. Lane r owns row 64b+r+1,
//   at step t computes column j = (t - r) + 1. up/diag flow via DPP wave_shr.
//   Band handoff through global `bottom` rows + agent-scope progress flags.
// R13: R12 (register staging + skewed coalesced loads) passed at 872 us but
//   still ~4400 cy/block vs ~1600 cy issue. Shrink the VMEM queue: the old
//   feed path was 16 loads/block of the SAME 12 B on all 64 lanes (8x
//   redundant broadcast, inflating the 63-op vmcnt window). Now: ONE
//   lane-parallel global_load_dword sc0 per block -- lanes 0..23 each carry
//   one float of the 24-float feed span (sc0 = L1 bypass, deleting the
//   stale-line hazard the acquire-inv was papering over). Distribution to
//   lane 0 via v_readlane with compile-time indices (3k,3k+1,3k+2; k
//   unrolled). Wait constant: newer-than-F(T) = P(1)+S(16) -> vmcnt(17)
//   (last band: 0). Theta staging, publish/poll, sc1 stores, DPP shup1,
//   head/mid/tail split: byte-for-byte R12.
// ---------------------------------------------------------------------------

#define MM 1536
#define HH 64
#define NB 24
#define U  8
#define NBLK 200                    // 200*8 = 1600 >= MM+HH-1 = 1599 steps
#define NSTEP 1608                  // staged t range: 0..1607 (incl. prefetch)
#define LOG2E 1.4426950408889634f
#define LN2   0.6931471805599453f
#define NEG2  (-1.4426950408889634e8f)   // (-1e8) * LOG2E (log2-domain -inf)

typedef float f32x4 __attribute__((ext_vector_type(4)));
typedef float f32x2 __attribute__((ext_vector_type(2)));

struct T9R { f32x4 q0; f32x4 q1; float s8; };   // one column, this lane's row

__device__ __forceinline__ float shup1(float x) {
    // lane L gets lane L-1's x (DPP wave_shr:1); lane 0 keeps its own value
    // (always overwritten by the feed select). Verified R7-R12 (absmax 0).
    int xi = __builtin_bit_cast(int, x);
    int r  = __builtin_amdgcn_update_dpp(xi, xi, 0x138, 0xF, 0xF, false);
    return __builtin_bit_cast(float, r);
}

__device__ __forceinline__ float lse3_2(float a, float b, float c) {
    // log2-domain LSE of 3: max3 + med3 + min3 (hw ops), 2 exp2 + 1 log2.
    float mx = fmaxf(fmaxf(a, b), c);
    float mn = fminf(fminf(a, b), c);
    float md = __builtin_amdgcn_fmed3f(a, b, c);
    return mx + __builtin_amdgcn_logf(1.0f + __builtin_amdgcn_exp2f(mn - mx)
                                           + __builtin_amdgcn_exp2f(md - mx));
}

__device__ __forceinline__ float rdlane(float v, int l) {
    return __builtin_bit_cast(float,
        __builtin_amdgcn_readlane(__builtin_bit_cast(int, v), l));
}

__global__ void init_progress_kernel(int* progress) {
    if (threadIdx.x < NB) progress[threadIdx.x] = -1;
}

// ---------------------------------------------------------------------------
// skew_kernel (PROVEN R9/R12): one wave per (band b, step t). Lane r reads
// theta record (row 64b+r, col t-r) -- scattered, hidden by 38592 concurrent
// waves -- writes the 2304-B skewed record with coalesced stores.
// Record layout (floats): [0,256) q0 (lane*4), [256,512) q1, [512,576) s8.
// ---------------------------------------------------------------------------
__global__ __launch_bounds__(256)
void skew_kernel(const float* __restrict__ theta, float* __restrict__ skew)
{
    const int wid  = blockIdx.x * 4 + (threadIdx.x >> 6);
    const int lane = threadIdx.x & 63;
    const int b = wid / NSTEP;
    const int t = wid - b * NSTEP;

    const int c = t - lane;
    float v[9];
    if ((unsigned)c < (unsigned)MM) {
        const float* g = theta + ((size_t)(b * HH + lane) * MM + c) * 9;
        __builtin_memcpy(&v[0], g, 36);
    } else {
        #pragma unroll
        for (int i = 0; i < 9; ++i) v[i] = 0.0f;
    }

    float* o = skew + (size_t)(b * NSTEP + t) * 576;
    f32x4 a; a.x = v[0]; a.y = v[1]; a.z = v[2]; a.w = v[3];
    f32x4 q; q.x = v[4]; q.y = v[5]; q.z = v[6]; q.w = v[7];
    *(f32x4*)(o + lane * 4)       = a;   // coalesced 1 KB
    *(f32x4*)(o + 256 + lane * 4) = q;   // coalesced 1 KB
    o[512 + lane] = v[8];                // coalesced 256 B
}

template <bool SKEW>
__global__ __launch_bounds__(64, 1)
void hmm_fwd_kernel(const float* __restrict__ src, float* __restrict__ out,
                    float* __restrict__ bottom, int* __restrict__ progress)
{
    const int b    = blockIdx.x;
    const int lane = threadIdx.x;
    const float* __restrict__ thp =
        SKEW ? nullptr : src + (size_t)(b * HH + lane) * (MM * 9);
    const float* __restrict__ skp =
        SKEW ? src + (size_t)b * NSTEP * 576 : nullptr;
    const float* __restrict__ bsrc =
        bottom + (size_t)(b > 0 ? b - 1 : 0) * ((MM + 1) * 3);
    float* __restrict__ bdst = bottom + (size_t)b * ((MM + 1) * 3);

    float d0, d1, d2, l0, l1, l2, s0, s1, s2, res0, res1, res2;
    d0 = d1 = d2 = (b == 0 && lane == 0) ? 0.0f : NEG2;   // V[0,0] = 0 border
    l0 = l1 = l2 = NEG2;
    s0 = s1 = s2 = NEG2;
    res0 = res1 = res2 = NEG2;

    T9R thA[U], thB[U];       // theta double buffer (registers)
    float fvA = NEG2, fvB = NEG2;  // feed double buffer: lane L<24 carries
                                   // bottom float (t0-dependent base + L)

    // per-lane feed offset: lanes 0..23 carry one float, others duplicate 23
    const int fL = lane < 24 ? lane : 23;

    auto issue_theta = [&](int tb, T9R (&nx)[U]) {
        if constexpr (SKEW) {
            #pragma unroll
            for (int k = 0; k < U; ++k) {
                const float* rec = skp + (size_t)(tb + k) * 576;
                const float* aq  = rec + (size_t)lane * 4;        // 16B/lane
                const float* as_ = rec + 512 + lane;              // 4B/lane
                asm volatile("global_load_dwordx4 %0, %1, off"
                             : "=v"(nx[k].q0) : "v"(aq));
                asm volatile("global_load_dwordx4 %0, %1, off offset:1024"
                             : "=v"(nx[k].q1) : "v"(aq));
                asm volatile("global_load_dword %0, %1, off"
                             : "=v"(nx[k].s8) : "v"(as_));
            }
        } else {
            #pragma unroll
            for (int k = 0; k < U; ++k) {
                int c = tb + k - lane;
                c = c < 0 ? 0 : (c > MM - 1 ? MM - 1 : c);
                struct P { float f[9]; } tmp;
                __builtin_memcpy(&tmp, thp + (size_t)c * 9, 36);
                nx[k].q0.x = tmp.f[0]; nx[k].q0.y = tmp.f[1];
                nx[k].q0.z = tmp.f[2]; nx[k].q0.w = tmp.f[3];
                nx[k].q1.x = tmp.f[4]; nx[k].q1.y = tmp.f[5];
                nx[k].q1.z = tmp.f[6]; nx[k].q1.w = tmp.f[7];
                nx[k].s8   = tmp.f[8];
            }
        }
    };
    // Feed for block X: 24 contiguous floats bsrc[3*(8X+1) .. +24); lane L
    // carries float base+L. ONE dword load sc0 (L1-bypass: producer updates
    // these lines continuously; sc0 reads L2-coherent data directly).
    auto issue_feed = [&](int X, float& fv) {
        if (b > 0) {
            int idx = 24 * X + 3 + fL;
            if (idx > 4610) idx = 4610;           // clamp inside bottom row
            const float* a = bsrc + idx;
            asm volatile("global_load_dword %0, %1, off sc0"
                         : "=v"(fv) : "v"(a));
        }
    };

    // pre-loop sync: covers prime F(0) (j<=8) + T=0's F(1) (j<=16) +
    // T=1's F(2) (j<=24)
    if (b > 0) {
        while (__hip_atomic_load(&progress[b - 1], __ATOMIC_ACQUIRE,
                                 __HIP_MEMORY_SCOPE_AGENT) < 24)
            __builtin_amdgcn_s_sleep(2);
    }

    // prime block 0 into the A buffers; full drain once (only cold stall)
    issue_theta(0, thA);
    issue_feed(0, fvA);
    asm volatile("s_waitcnt vmcnt(0)" ::: "memory");
    __builtin_amdgcn_sched_barrier(0);

    auto block_body = [&](int T, T9R (&cur)[U], T9R (&nxt)[U],
                          float& fcur, float& fnxt,
                          bool mlo, bool mhi) {
        const int t0 = T * U;

        // consumer poll (even blocks): guarantee feed cols through t0+24,
        // covering F(T+1) (j<=t0+16) and F(T+2) (j<=t0+24).
        if (b > 0 && T > 0 && (T & 1) == 0) {
            int need = t0 + 24; if (need > MM) need = MM;
            while (__hip_atomic_load(&progress[b - 1], __ATOMIC_ACQUIRE,
                                     __HIP_MEMORY_SCOPE_AGENT) < need)
                __builtin_amdgcn_s_sleep(2);
        }

        // ONE counted wait per block, BEFORE issuing L(T+1)/F(T+1).
        // Queue at this point (oldest->newest): [residue <=17], L(T) 24,
        // F(T) 1, P(T-1) 1, S(T-1) 16. Newer-than-F(T) = 17, so vmcnt(17)
        // retires L(T), F(T), and S(<=T-2) (publish safety). Last band has
        // no P/S -> drain fully (nothing in flight worth keeping).
        if (b < NB - 1) asm volatile("s_waitcnt vmcnt(17)" ::: "memory");
        else            asm volatile("s_waitcnt vmcnt(0)"  ::: "memory");

        // issue L(T+1)/F(T+1) (in flight across this whole block's compute)
        issue_theta(t0 + U, nxt);
        issue_feed(T + 1, fnxt);

        // publish: sc1 stores are device-visible once vmcnt-retired (done
        // above for S(<=T-2)) -> RELAXED store suffices. val = t0-71 covers
        // columns through block T-2 (lane63's last col there = t0-72).
        if (b < NB - 1 && lane == HH - 1) {
            int val = t0 - 71;
            if (val >= 1) {
                if (val > MM) val = MM;
                __hip_atomic_store(&progress[b], val, __ATOMIC_RELAXED,
                                   __HIP_MEMORY_SCOPE_AGENT);
            }
        }
        __builtin_amdgcn_sched_barrier(0);

        // compute 8 columns from the resident register buffers
        #pragma unroll
        for (int k = 0; k < U; ++k) {
            const int c = t0 + k - lane;
            bool act = true;
            if (mlo || mhi) act = ((unsigned)c < (unsigned)MM);

            // feed floats for this column live on lanes 3k..3k+2 of fcur
            const float u0s = rdlane(fcur, 3 * k);
            const float u1s = rdlane(fcur, 3 * k + 1);
            const float u2s = rdlane(fcur, 3 * k + 2);
            float u0 = (lane == 0) ? u0s : s0;
            float u1 = (lane == 0) ? u1s : s1;
            float u2 = (lane == 0) ? u2s : s2;

            float aa0 = fmaf(cur[k].q0.x, LOG2E, d0);
            float aa1 = fmaf(cur[k].q0.y, LOG2E, d1);
            float aa2 = fmaf(cur[k].q0.z, LOG2E, d2);
            float bb0 = fmaf(cur[k].q0.w, LOG2E, u0);
            float bb1 = fmaf(cur[k].q1.x, LOG2E, u1);
            float bb2 = fmaf(cur[k].q1.y, LOG2E, u2);
            float cc0 = fmaf(cur[k].q1.z, LOG2E, l0);
            float cc1 = fmaf(cur[k].q1.w, LOG2E, l1);
            float cc2 = fmaf(cur[k].s8,   LOG2E, l2);

            float n0 = lse3_2(aa0, aa1, aa2);
            float n1 = lse3_2(bb0, bb1, bb2);
            float n2 = lse3_2(cc0, cc1, cc2);
            if (mlo || mhi) {
                n0 = act ? n0 : NEG2;
                n1 = act ? n1 : NEG2;
                n2 = act ? n2 : NEG2;
            }

            // producer: lane 63 streams the bottom row. sc1 = device scope.
            // DETERMINISTIC 16 stores/block: inactive cols -> slot j=0
            // (never read; feeds start at j>=1).
            if (b < NB - 1 && lane == HH - 1) {
                int j = c + 1;
                if (mlo || mhi) j = act ? c + 1 : 0;
                float* sa = bdst + (size_t)j * 3;
                f32x2 p01; p01.x = n0; p01.y = n1;
                asm volatile("global_store_dwordx2 %0, %1, off sc1"
                             :: "v"(sa), "v"(p01) : "memory");
                asm volatile("global_store_dword %0, %1, off offset:8 sc1"
                             :: "v"(sa), "v"(n2) : "memory");
            }

            if (mhi) {   // capture V[N,M]: lane63 hits c==MM-1 at T=199
                const bool fin = (c == MM - 1);
                res0 = fin ? n0 : res0;
                res1 = fin ? n1 : res1;
                res2 = fin ? n2 : res2;
            }

            // rotate wavefront state
            d0 = u0; d1 = u1; d2 = u2;
            s0 = shup1(n0);
            s1 = shup1(n1);
            s2 = shup1(n2);
            l0 = n0; l1 = n1; l2 = n2;
        }
    };

    // head (mask low edge) / mid (no mask, no fin) / tail (mask high + fin).
    // c range: T>=8 -> c >= 64-63 = 1 >= 0; T<=191 -> c <= 1528+7 = 1535 < MM.
    for (int T = 0; T < 8; T += 2) {
        block_body(T,     thA, thB, fvA, fvB, true, false);
        block_body(T + 1, thB, thA, fvB, fvA, true, false);
    }
    for (int T = 8; T < 192; T += 2) {
        block_body(T,     thA, thB, fvA, fvB, false, false);
        block_body(T + 1, thB, thA, fvB, fvA, false, false);
    }
    for (int T = 192; T < NBLK; T += 2) {
        block_body(T,     thA, thB, fvA, fvB, false, true);
        block_body(T + 1, thB, thA, fvB, fvA, false, true);
    }

    // final publish: release + full drain (bulletproof tail handoff)
    if (b < NB - 1 && lane == HH - 1) {
        asm volatile("s_waitcnt vmcnt(0)" ::: "memory");
        __hip_atomic_store(&progress[b], MM, __ATOMIC_RELEASE,
                           __HIP_MEMORY_SCOPE_AGENT);
    }

    if (b == NB - 1 && lane == HH - 1)
        out[0] = LN2 * lse3_2(res0, res1, res2);
}

extern "C" void kernel_launch(void* const* d_in, const int* in_sizes, int n_in,
                              void* d_out, int out_size, void* d_ws, size_t ws_size,
                              hipStream_t stream)
{
    const float* theta = (const float*)d_in[0];
    float* out = (float*)d_out;

    const size_t skew_fl = (size_t)NB * NSTEP * 576;      // 88.9 MB
    const size_t bot_fl  = (size_t)NB * (MM + 1) * 3;     // 442 KB
    const size_t need    = (skew_fl + bot_fl) * sizeof(float) + NB * sizeof(int);

    if (ws_size >= need) {
        float* skew     = (float*)d_ws;
        float* bottom   = skew + skew_fl;
        int*   progress = (int*)(bottom + bot_fl);
        init_progress_kernel<<<1, 64, 0, stream>>>(progress);
        skew_kernel<<<(NB * NSTEP) / 4, 256, 0, stream>>>(theta, skew);
        hmm_fwd_kernel<true><<<NB, HH, 0, stream>>>(skew, out, bottom, progress);
    } else {
        float* bottom   = (float*)d_ws;
        int*   progress = (int*)((char*)d_ws + bot_fl * sizeof(float));
        init_progress_kernel<<<1, 64, 0, stream>>>(progress);
        hmm_fwd_kernel<false><<<NB, HH, 0, stream>>>(theta, out, bottom, progress);
    }
}